// Round 2
// baseline (415.706 us; speedup 1.0000x reference)
//
#include <hip/hip_runtime.h>
#include <cstdint>
#include <cstddef>

#define T_TOK 8192
#define DDIM 1024
#define FDIM 2048
#define NEXP 8

typedef _Float16 f16x8 __attribute__((ext_vector_type(8)));
typedef _Float16 f16x4 __attribute__((ext_vector_type(4)));
typedef float f32x4 __attribute__((ext_vector_type(4)));

__device__ __forceinline__ void gl_lds16(const void* g, void* s) {
  __builtin_amdgcn_global_load_lds(
      (const __attribute__((address_space(1))) void*)g,
      (__attribute__((address_space(3))) void*)s, 16, 0, 0);
}

// ---------------- init ----------------
__global__ void k_init(int* counts, int* cursors, float* scores) {
  int i = threadIdx.x;
  if (i < NEXP) { counts[i] = 0; cursors[i] = 0; scores[i] = 0.f; }
}

// ---------------- gating (fp64 accumulate for exact argmax) ----------------
__global__ __launch_bounds__(256) void k_gate(
    const float* __restrict__ x, const float* __restrict__ gW,
    const float* __restrict__ gb, int* __restrict__ idx,
    float* __restrict__ wgt, int* __restrict__ counts,
    float* __restrict__ scores) {
  int wid = threadIdx.x >> 6, lane = threadIdx.x & 63;
  int t = blockIdx.x * 4 + wid;
  const float* xr = x + (size_t)t * DDIM;
  double acc[NEXP];
#pragma unroll
  for (int e = 0; e < NEXP; ++e) acc[e] = 0.0;
  for (int d = lane; d < DDIM; d += 64) {
    double xv = (double)xr[d];
    const float* wr = gW + d * NEXP;
#pragma unroll
    for (int e = 0; e < NEXP; ++e) acc[e] += xv * (double)wr[e];
  }
#pragma unroll
  for (int off = 32; off > 0; off >>= 1) {
#pragma unroll
    for (int e = 0; e < NEXP; ++e) acc[e] += __shfl_down(acc[e], off, 64);
  }
  if (lane == 0) {
    double mx = -1e300; int am = 0;
#pragma unroll
    for (int e = 0; e < NEXP; ++e) {
      acc[e] += (double)gb[e];
      if (acc[e] > mx) { mx = acc[e]; am = e; }
    }
    double s = 0.0;
#pragma unroll
    for (int e = 0; e < NEXP; ++e) s += exp(acc[e] - mx);
    float w = (float)(1.0 / s);  // max prob = exp(0)/sum
    idx[t] = am; wgt[t] = w;
    atomicAdd(&counts[am], 1);
    atomicAdd(&scores[am], w);
  }
}

// ---------------- offsets + loss ----------------
__global__ void k_offsets_loss(const int* counts, const float* scores,
                               int* offs, float* loss_out) {
  if (threadIdx.x == 0) {
    int off = 0; float loss = 0.f;
    for (int e = 0; e < NEXP; ++e) {
      offs[e] = off; off += counts[e];
      float usage = scores[e] / ((float)counts[e] + 1e-8f);
      float d = usage - (1.0f / NEXP);
      loss += d * d;
    }
    loss_out[0] = loss;
  }
}

// ---------------- scatter (token -> permuted position) ----------------
__global__ __launch_bounds__(256) void k_scatter(
    const int* __restrict__ idx, const int* __restrict__ offs,
    int* __restrict__ cursors, int* __restrict__ perm) {
  int t = blockIdx.x * 256 + threadIdx.x;
  int e = idx[t];
  int pos = offs[e] + atomicAdd(&cursors[e], 1);
  perm[pos] = t;
}

// ---------------- transpose + fp32->fp16 convert ----------------
// src [z][R][C] fp32 -> dst [z][C][R] fp16
__global__ __launch_bounds__(256) void k_transpose_cvt(
    const float* __restrict__ src, _Float16* __restrict__ dst, int R, int C) {
  __shared__ _Float16 tile[32][33];
  int tx = threadIdx.x & 31, ty = threadIdx.x >> 5;
  size_t base = (size_t)blockIdx.z * (size_t)R * (size_t)C;
  int c0 = blockIdx.x * 32, r0 = blockIdx.y * 32;
  const float* s = src + base;
  _Float16* d = dst + base;
#pragma unroll
  for (int i = 0; i < 32; i += 8)
    tile[ty + i][tx] = (_Float16)s[(size_t)(r0 + ty + i) * C + c0 + tx];
  __syncthreads();
#pragma unroll
  for (int i = 0; i < 32; i += 8)
    d[(size_t)(c0 + ty + i) * R + r0 + tx] = tile[tx][ty + i];
}

// ---------------- gather tokens + fp32->fp16 ----------------
__global__ __launch_bounds__(256) void k_gather_cvt(
    const float* __restrict__ x, const int* __restrict__ perm,
    _Float16* __restrict__ Xg) {
  int p = blockIdx.x;
  int t = perm[p];
  const float4* srow = (const float4*)(x + (size_t)t * DDIM);
  f16x4* drow = (f16x4*)(Xg + (size_t)p * DDIM);
  float4 v = srow[threadIdx.x];
  f16x4 h = { (_Float16)v.x, (_Float16)v.y, (_Float16)v.z, (_Float16)v.w };
  drow[threadIdx.x] = h;
}

// ---------------- GEMM1 + GLU epilogue ----------------
// H = Xg[seg] @ W[e] + b ; G = x1 * x2 * 0.5*(1+erf(x2/sqrt2))
// Wt layout: [e][4096][1024] fp16 (row n = output col, K contiguous)
__global__ __launch_bounds__(256) void k_gemm1_glu(
    const _Float16* __restrict__ Xg, const _Float16* __restrict__ Wt,
    const float* __restrict__ fcb, const int* __restrict__ offs,
    const int* __restrict__ counts, _Float16* __restrict__ G) {
  int e = blockIdx.y >> 6;
  int m0 = (blockIdx.y & 63) * 128;
  int n_e = counts[e];
  if (m0 >= n_e) return;
  int seg = offs[e];
  int n0 = blockIdx.x * 64;

  __shared__ __align__(16) _Float16 As[128][32];
  __shared__ __align__(16) _Float16 B1s[64][32];
  __shared__ __align__(16) _Float16 B2s[64][32];

  int tid = threadIdx.x;
  int wid = tid >> 6, lane = tid & 63;
  int wm = wid >> 1, wn = wid & 1;

  const _Float16* We = Wt + (size_t)e * (4096ull * 1024ull);
  const float* fcbe = fcb + e * 4096;

  int srow = tid >> 2;
  int scol = (tid & 3) * 8;
  int ar0 = min(seg + m0 + srow, T_TOK - 1);
  int ar1 = min(seg + m0 + 64 + srow, T_TOK - 1);
  const _Float16* gA0 = Xg + (size_t)ar0 * DDIM + scol;
  const _Float16* gA1 = Xg + (size_t)ar1 * DDIM + scol;
  const _Float16* gB1 = We + (size_t)(n0 + srow) * DDIM + scol;
  const _Float16* gB2 = We + (size_t)(2048 + n0 + srow) * DDIM + scol;
  _Float16* lA0 = &As[0][0] + tid * 8;
  _Float16* lA1 = &As[0][0] + 2048 + tid * 8;
  _Float16* lB1 = &B1s[0][0] + tid * 8;
  _Float16* lB2 = &B2s[0][0] + tid * 8;

  f32x4 acc1[4][2], acc2[4][2];
#pragma unroll
  for (int a = 0; a < 4; ++a)
#pragma unroll
    for (int b = 0; b < 2; ++b) {
      acc1[a][b] = (f32x4){0.f, 0.f, 0.f, 0.f};
      acc2[a][b] = (f32x4){0.f, 0.f, 0.f, 0.f};
    }

  int lr = lane & 15;
  int lk = (lane >> 4) * 8;

  for (int k0 = 0; k0 < DDIM; k0 += 32) {
    gl_lds16(gA0 + k0, lA0);
    gl_lds16(gA1 + k0, lA1);
    gl_lds16(gB1 + k0, lB1);
    gl_lds16(gB2 + k0, lB2);
    __syncthreads();
    f16x8 a[4], b1[2], b2[2];
#pragma unroll
    for (int mf = 0; mf < 4; ++mf)
      a[mf] = *(const f16x8*)&As[wm * 64 + mf * 16 + lr][lk];
#pragma unroll
    for (int nf = 0; nf < 2; ++nf) {
      b1[nf] = *(const f16x8*)&B1s[wn * 32 + nf * 16 + lr][lk];
      b2[nf] = *(const f16x8*)&B2s[wn * 32 + nf * 16 + lr][lk];
    }
#pragma unroll
    for (int mf = 0; mf < 4; ++mf)
#pragma unroll
      for (int nf = 0; nf < 2; ++nf) {
        acc1[mf][nf] = __builtin_amdgcn_mfma_f32_16x16x32_f16(a[mf], b1[nf], acc1[mf][nf], 0, 0, 0);
        acc2[mf][nf] = __builtin_amdgcn_mfma_f32_16x16x32_f16(a[mf], b2[nf], acc2[mf][nf], 0, 0, 0);
      }
    __syncthreads();
  }

  int lk4 = (lane >> 4) * 4;
#pragma unroll
  for (int mf = 0; mf < 4; ++mf) {
#pragma unroll
    for (int i = 0; i < 4; ++i) {
      int pl = m0 + wm * 64 + mf * 16 + lk4 + i;
      if (pl >= n_e) continue;
      size_t grow = (size_t)(seg + pl) * FDIM;
#pragma unroll
      for (int nf = 0; nf < 2; ++nf) {
        int col = n0 + wn * 32 + nf * 16 + lr;
        float x1 = acc1[mf][nf][i] + fcbe[col];
        float x2v = acc2[mf][nf][i] + fcbe[2048 + col];
        // exact GELU: gelu(x2) = x2 * 0.5*(1+erf(x2/sqrt(2)))
        float g = x1 * x2v * 0.5f * (1.0f + erff(x2v * 0.70710678118654752f));
        G[grow + col] = (_Float16)g;
      }
    }
  }
}

// ---------------- GEMM2 + bias + weight scale + scatter ----------------
// out[t] = (G[seg] @ V[e] + out_b[e]) * w[t]
// Vt layout: [e][1024][2048] fp16 (row d = output col, K contiguous)
__global__ __launch_bounds__(256) void k_gemm2_out(
    const _Float16* __restrict__ G, const _Float16* __restrict__ Vt,
    const float* __restrict__ ob, const int* __restrict__ offs,
    const int* __restrict__ counts, const int* __restrict__ perm,
    const float* __restrict__ wgt, float* __restrict__ out) {
  int e = blockIdx.y >> 6;
  int m0 = (blockIdx.y & 63) * 128;
  int n_e = counts[e];
  if (m0 >= n_e) return;
  int seg = offs[e];
  int n0 = blockIdx.x * 128;

  __shared__ __align__(16) _Float16 As[128][32];
  __shared__ __align__(16) _Float16 Bs[128][32];

  int tid = threadIdx.x, wid = tid >> 6, lane = tid & 63;
  int wm = wid >> 1, wn = wid & 1;
  const _Float16* Ve = Vt + (size_t)e * (1024ull * 2048ull);
  const float* obe = ob + e * 1024;

  int srow = tid >> 2, scol = (tid & 3) * 8;
  int ar0 = min(seg + m0 + srow, T_TOK - 1);
  int ar1 = min(seg + m0 + 64 + srow, T_TOK - 1);
  const _Float16* gA0 = G + (size_t)ar0 * FDIM + scol;
  const _Float16* gA1 = G + (size_t)ar1 * FDIM + scol;
  const _Float16* gB0 = Ve + (size_t)(n0 + srow) * FDIM + scol;
  const _Float16* gB1 = Ve + (size_t)(n0 + 64 + srow) * FDIM + scol;
  _Float16* lA0 = &As[0][0] + tid * 8;
  _Float16* lA1 = &As[0][0] + 2048 + tid * 8;
  _Float16* lB0 = &Bs[0][0] + tid * 8;
  _Float16* lB1 = &Bs[0][0] + 2048 + tid * 8;

  f32x4 acc[4][4];
#pragma unroll
  for (int a = 0; a < 4; ++a)
#pragma unroll
    for (int b = 0; b < 4; ++b) acc[a][b] = (f32x4){0.f, 0.f, 0.f, 0.f};

  int lr = lane & 15;
  int lk = (lane >> 4) * 8;

  for (int k0 = 0; k0 < FDIM; k0 += 32) {
    gl_lds16(gA0 + k0, lA0);
    gl_lds16(gA1 + k0, lA1);
    gl_lds16(gB0 + k0, lB0);
    gl_lds16(gB1 + k0, lB1);
    __syncthreads();
    f16x8 a[4], b[4];
#pragma unroll
    for (int mf = 0; mf < 4; ++mf)
      a[mf] = *(const f16x8*)&As[wm * 64 + mf * 16 + lr][lk];
#pragma unroll
    for (int nf = 0; nf < 4; ++nf)
      b[nf] = *(const f16x8*)&Bs[wn * 64 + nf * 16 + lr][lk];
#pragma unroll
    for (int mf = 0; mf < 4; ++mf)
#pragma unroll
      for (int nf = 0; nf < 4; ++nf)
        acc[mf][nf] = __builtin_amdgcn_mfma_f32_16x16x32_f16(a[mf], b[nf], acc[mf][nf], 0, 0, 0);
    __syncthreads();
  }

  int lk4 = (lane >> 4) * 4;
#pragma unroll
  for (int mf = 0; mf < 4; ++mf) {
#pragma unroll
    for (int i = 0; i < 4; ++i) {
      int pl = m0 + wm * 64 + mf * 16 + lk4 + i;
      if (pl >= n_e) continue;
      int p = seg + pl;
      int t = perm[p];
      float wv = wgt[t];
      float* orow = out + (size_t)t * DDIM;
#pragma unroll
      for (int nf = 0; nf < 4; ++nf) {
        int col = n0 + wn * 64 + nf * 16 + lr;
        orow[col] = (acc[mf][nf][i] + obe[col]) * wv;
      }
    }
  }
}

extern "C" void kernel_launch(void* const* d_in, const int* in_sizes, int n_in,
                              void* d_out, int out_size, void* d_ws, size_t ws_size,
                              hipStream_t stream) {
  const float* x   = (const float*)d_in[0];
  const float* gW  = (const float*)d_in[1];
  const float* gb  = (const float*)d_in[2];
  const float* fcW = (const float*)d_in[3];
  const float* fcb = (const float*)d_in[4];
  const float* oW  = (const float*)d_in[5];
  const float* ob  = (const float*)d_in[6];
  float* out = (float*)d_out;

  char* p = (char*)d_ws;
  _Float16* fcWt  = (_Float16*)p; p += (size_t)NEXP * 4096 * 1024 * 2;   // 67.1 MB
  _Float16* outWt = (_Float16*)p; p += (size_t)NEXP * 1024 * 2048 * 2;   // 33.6 MB
  _Float16* Xg    = (_Float16*)p; p += (size_t)T_TOK * DDIM * 2;         // 16.8 MB
  _Float16* G     = (_Float16*)p; p += (size_t)T_TOK * FDIM * 2;         // 33.6 MB
  int*   idx     = (int*)p;   p += T_TOK * 4;
  float* wgt     = (float*)p; p += T_TOK * 4;
  int*   perm    = (int*)p;   p += T_TOK * 4;
  int*   counts  = (int*)p;   p += 64;
  int*   cursors = (int*)p;   p += 64;
  int*   offs    = (int*)p;   p += 64;
  float* scores  = (float*)p; p += 64;

  k_init<<<1, 64, 0, stream>>>(counts, cursors, scores);
  k_gate<<<T_TOK / 4, 256, 0, stream>>>(x, gW, gb, idx, wgt, counts, scores);
  k_offsets_loss<<<1, 64, 0, stream>>>(counts, scores, offs, out + (size_t)T_TOK * DDIM);
  k_scatter<<<T_TOK / 256, 256, 0, stream>>>(idx, offs, cursors, perm);
  // weight conversions (independent of routing)
  k_transpose_cvt<<<dim3(4096 / 32, 1024 / 32, NEXP), 256, 0, stream>>>(fcW, fcWt, 1024, 4096);
  k_transpose_cvt<<<dim3(1024 / 32, 2048 / 32, NEXP), 256, 0, stream>>>(oW, outWt, 2048, 1024);
  k_gather_cvt<<<T_TOK, 256, 0, stream>>>(x, perm, Xg);
  k_gemm1_glu<<<dim3(2048 / 64, NEXP * 64), 256, 0, stream>>>(Xg, fcWt, fcb, offs, counts, G);
  k_gemm2_out<<<dim3(1024 / 128, NEXP * 64), 256, 0, stream>>>(G, outWt, ob, offs, counts, perm, wgt, out);
}

// Round 4
// 302.201 us; speedup vs baseline: 1.3756x; 1.3756x over previous
//
#include <hip/hip_runtime.h>
#include <cstdint>
#include <cstddef>

#define T_TOK 8192
#define DDIM 1024
#define FDIM 2048
#define NEXP 8

typedef _Float16 f16x8 __attribute__((ext_vector_type(8)));
typedef _Float16 f16x4 __attribute__((ext_vector_type(4)));
typedef float f32x4 __attribute__((ext_vector_type(4)));

__device__ __forceinline__ void gl_lds16(const void* g, void* s) {
  __builtin_amdgcn_global_load_lds(
      (const __attribute__((address_space(1))) void*)g,
      (__attribute__((address_space(3))) void*)s, 16, 0, 0);
}

// ---------------- gating (fp64 accumulate, no atomics) ----------------
// One wave per 2 tokens. 4 chunks of 256 dims; per chunk lane l holds
// gW rows 256*ch+4l .. +3 (32 floats) in registers.
__global__ __launch_bounds__(256) void k_gate(
    const float* __restrict__ x, const float* __restrict__ gW,
    const float* __restrict__ gb, int* __restrict__ idx,
    float* __restrict__ wgt) {
  int wid = threadIdx.x >> 6, lane = threadIdx.x & 63;
  int wave = blockIdx.x * 4 + wid;
  int t0 = wave * 2;

  double acc[2][NEXP];
#pragma unroll
  for (int tk = 0; tk < 2; ++tk)
#pragma unroll
    for (int e = 0; e < NEXP; ++e) acc[tk][e] = 0.0;

#pragma unroll
  for (int ch = 0; ch < 4; ++ch) {
    int dbase = ch * 256 + 4 * lane;  // this lane's 4 rows
    const f32x4* wp = (const f32x4*)(gW + (size_t)dbase * NEXP);
    f32x4 wv[8];
#pragma unroll
    for (int i = 0; i < 8; ++i) wv[i] = wp[i];
#pragma unroll
    for (int tk = 0; tk < 2; ++tk) {
      f32x4 xv = *(const f32x4*)(x + (size_t)(t0 + tk) * DDIM + dbase);
#pragma unroll
      for (int j = 0; j < 4; ++j) {
        double xd = (double)xv[j];
#pragma unroll
        for (int e = 0; e < NEXP; ++e)
          acc[tk][e] += xd * (double)wv[2 * j + (e >> 2)][e & 3];
      }
    }
  }

#pragma unroll
  for (int off = 32; off > 0; off >>= 1) {
#pragma unroll
    for (int tk = 0; tk < 2; ++tk)
#pragma unroll
      for (int e = 0; e < NEXP; ++e)
        acc[tk][e] += __shfl_xor(acc[tk][e], off, 64);
  }
  if (lane == 0) {
#pragma unroll
    for (int tk = 0; tk < 2; ++tk) {
      double mx = -1e300; int am = 0;
#pragma unroll
      for (int e = 0; e < NEXP; ++e) {
        acc[tk][e] += (double)gb[e];
        if (acc[tk][e] > mx) { mx = acc[tk][e]; am = e; }
      }
      double s = 0.0;
#pragma unroll
      for (int e = 0; e < NEXP; ++e) s += exp(acc[tk][e] - mx);
      idx[t0 + tk] = am;
      wgt[t0 + tk] = (float)(1.0 / s);
    }
  }
}

// ---------------- routing: counts/offsets/loss + stable rank scatter ------
// Single block, 1024 threads (16 waves), 8 chunks of 1024 tokens.
__global__ __launch_bounds__(1024) void k_route(
    const int* __restrict__ idx, const float* __restrict__ wgt,
    int* __restrict__ perm, int* __restrict__ counts_out,
    int* __restrict__ offs_out, float* __restrict__ loss_out) {
  __shared__ int cnt_ws[16][NEXP];
  __shared__ float sc_ws[16][NEXP];
  __shared__ int wprefix[16][NEXP];
  __shared__ int base[NEXP];

  int tid = threadIdx.x, w = tid >> 6, lane = tid & 63;

  // ---- pass 1: totals ----
  int c_e[NEXP];
  float s_e[NEXP];
#pragma unroll
  for (int e = 0; e < NEXP; ++e) { c_e[e] = 0; s_e[e] = 0.f; }
  for (int c = 0; c < 8; ++c) {
    int t = c * 1024 + tid;
    int my = idx[t];
    float mw = wgt[t];
#pragma unroll
    for (int e = 0; e < NEXP; ++e) {
      unsigned long long m = __ballot(my == e);
      if (lane == 0) c_e[e] += (int)__popcll(m);
      s_e[e] += (my == e) ? mw : 0.f;
    }
  }
#pragma unroll
  for (int off = 32; off > 0; off >>= 1) {
#pragma unroll
    for (int e = 0; e < NEXP; ++e) s_e[e] += __shfl_xor(s_e[e], off, 64);
  }
  if (lane == 0) {
#pragma unroll
    for (int e = 0; e < NEXP; ++e) { cnt_ws[w][e] = c_e[e]; sc_ws[w][e] = s_e[e]; }
  }
  __syncthreads();
  if (tid == 0) {
    int tot[NEXP]; float sct[NEXP];
#pragma unroll
    for (int e = 0; e < NEXP; ++e) { tot[e] = 0; sct[e] = 0.f; }
    for (int ww = 0; ww < 16; ++ww)
#pragma unroll
      for (int e = 0; e < NEXP; ++e) { tot[e] += cnt_ws[ww][e]; sct[e] += sc_ws[ww][e]; }
    int off = 0; float loss = 0.f;
#pragma unroll
    for (int e = 0; e < NEXP; ++e) {
      offs_out[e] = off; counts_out[e] = tot[e];
      base[e] = off;
      off += tot[e];
      float usage = sct[e] / ((float)tot[e] + 1e-8f);
      float d = usage - (1.0f / NEXP);
      loss += d * d;
    }
    loss_out[0] = loss;
  }
  __syncthreads();

  // ---- pass 2: stable rank scatter ----
  unsigned long long lt_mask = ((unsigned long long)1 << lane) - 1ull;
  for (int c = 0; c < 8; ++c) {
    int t = c * 1024 + tid;
    int my = idx[t];
    int rank_w = 0;
    int wcnt[NEXP];
#pragma unroll
    for (int e = 0; e < NEXP; ++e) {
      unsigned long long m = __ballot(my == e);
      if (my == e) rank_w = (int)__popcll(m & lt_mask);
      wcnt[e] = (int)__popcll(m);
    }
    if (lane == 0) {
#pragma unroll
      for (int e = 0; e < NEXP; ++e) cnt_ws[w][e] = wcnt[e];
    }
    __syncthreads();
    if (tid < 128) {
      int ww = tid >> 3, e = tid & 7;
      int p = 0;
      for (int w2 = 0; w2 < 16; ++w2) if (w2 < ww) p += cnt_ws[w2][e];
      wprefix[ww][e] = p;
    }
    __syncthreads();
    int pos = base[my] + wprefix[w][my] + rank_w;
    perm[pos] = t;
    __syncthreads();
    if (tid < 8) base[tid] += wprefix[15][tid] + cnt_ws[15][tid];
    __syncthreads();
  }
}

// ---------------- transpose + fp32->fp16 convert ----------------
// src [z][R][C] fp32 -> dst [z][C][R] fp16
__global__ __launch_bounds__(256) void k_transpose_cvt(
    const float* __restrict__ src, _Float16* __restrict__ dst, int R, int C) {
  __shared__ _Float16 tile[32][33];
  int tx = threadIdx.x & 31, ty = threadIdx.x >> 5;
  size_t base = (size_t)blockIdx.z * (size_t)R * (size_t)C;
  int c0 = blockIdx.x * 32, r0 = blockIdx.y * 32;
  const float* s = src + base;
  _Float16* d = dst + base;
#pragma unroll
  for (int i = 0; i < 32; i += 8)
    tile[ty + i][tx] = (_Float16)s[(size_t)(r0 + ty + i) * C + c0 + tx];
  __syncthreads();
#pragma unroll
  for (int i = 0; i < 32; i += 8)
    d[(size_t)(c0 + ty + i) * R + r0 + tx] = tile[tx][ty + i];
}

// ---------------- gather tokens + fp32->fp16 ----------------
__global__ __launch_bounds__(256) void k_gather_cvt(
    const float* __restrict__ x, const int* __restrict__ perm,
    _Float16* __restrict__ Xg) {
  int p = blockIdx.x;
  int t = perm[p];
  const float4* srow = (const float4*)(x + (size_t)t * DDIM);
  f16x4* drow = (f16x4*)(Xg + (size_t)p * DDIM);
  float4 v = srow[threadIdx.x];
  f16x4 h = { (_Float16)v.x, (_Float16)v.y, (_Float16)v.z, (_Float16)v.w };
  drow[threadIdx.x] = h;
}

// ---------------- GEMM1 + GLU epilogue ----------------
__global__ __launch_bounds__(256) void k_gemm1_glu(
    const _Float16* __restrict__ Xg, const _Float16* __restrict__ Wt,
    const float* __restrict__ fcb, const int* __restrict__ offs,
    const int* __restrict__ counts, _Float16* __restrict__ G) {
  int e = blockIdx.y >> 6;
  int m0 = (blockIdx.y & 63) * 128;
  int n_e = counts[e];
  if (m0 >= n_e) return;
  int seg = offs[e];
  int n0 = blockIdx.x * 64;

  __shared__ __align__(16) _Float16 As[128][32];
  __shared__ __align__(16) _Float16 B1s[64][32];
  __shared__ __align__(16) _Float16 B2s[64][32];

  int tid = threadIdx.x;
  int wid = tid >> 6, lane = tid & 63;
  int wm = wid >> 1, wn = wid & 1;

  const _Float16* We = Wt + (size_t)e * (4096ull * 1024ull);
  const float* fcbe = fcb + e * 4096;

  int srow = tid >> 2;
  int scol = (tid & 3) * 8;
  int ar0 = min(seg + m0 + srow, T_TOK - 1);
  int ar1 = min(seg + m0 + 64 + srow, T_TOK - 1);
  const _Float16* gA0 = Xg + (size_t)ar0 * DDIM + scol;
  const _Float16* gA1 = Xg + (size_t)ar1 * DDIM + scol;
  const _Float16* gB1 = We + (size_t)(n0 + srow) * DDIM + scol;
  const _Float16* gB2 = We + (size_t)(2048 + n0 + srow) * DDIM + scol;
  _Float16* lA0 = &As[0][0] + tid * 8;
  _Float16* lA1 = &As[0][0] + 2048 + tid * 8;
  _Float16* lB1 = &B1s[0][0] + tid * 8;
  _Float16* lB2 = &B2s[0][0] + tid * 8;

  f32x4 acc1[4][2], acc2[4][2];
#pragma unroll
  for (int a = 0; a < 4; ++a)
#pragma unroll
    for (int b = 0; b < 2; ++b) {
      acc1[a][b] = (f32x4){0.f, 0.f, 0.f, 0.f};
      acc2[a][b] = (f32x4){0.f, 0.f, 0.f, 0.f};
    }

  int lr = lane & 15;
  int lk = (lane >> 4) * 8;

  for (int k0 = 0; k0 < DDIM; k0 += 32) {
    gl_lds16(gA0 + k0, lA0);
    gl_lds16(gA1 + k0, lA1);
    gl_lds16(gB1 + k0, lB1);
    gl_lds16(gB2 + k0, lB2);
    __syncthreads();
    f16x8 a[4], b1[2], b2[2];
#pragma unroll
    for (int mf = 0; mf < 4; ++mf)
      a[mf] = *(const f16x8*)&As[wm * 64 + mf * 16 + lr][lk];
#pragma unroll
    for (int nf = 0; nf < 2; ++nf) {
      b1[nf] = *(const f16x8*)&B1s[wn * 32 + nf * 16 + lr][lk];
      b2[nf] = *(const f16x8*)&B2s[wn * 32 + nf * 16 + lr][lk];
    }
#pragma unroll
    for (int mf = 0; mf < 4; ++mf)
#pragma unroll
      for (int nf = 0; nf < 2; ++nf) {
        acc1[mf][nf] = __builtin_amdgcn_mfma_f32_16x16x32_f16(a[mf], b1[nf], acc1[mf][nf], 0, 0, 0);
        acc2[mf][nf] = __builtin_amdgcn_mfma_f32_16x16x32_f16(a[mf], b2[nf], acc2[mf][nf], 0, 0, 0);
      }
    __syncthreads();
  }

  int lk4 = (lane >> 4) * 4;
#pragma unroll
  for (int mf = 0; mf < 4; ++mf) {
#pragma unroll
    for (int i = 0; i < 4; ++i) {
      int pl = m0 + wm * 64 + mf * 16 + lk4 + i;
      if (pl >= n_e) continue;
      size_t grow = (size_t)(seg + pl) * FDIM;
#pragma unroll
      for (int nf = 0; nf < 2; ++nf) {
        int col = n0 + wn * 32 + nf * 16 + lr;
        float x1 = acc1[mf][nf][i] + fcbe[col];
        float x2v = acc2[mf][nf][i] + fcbe[2048 + col];
        float g = x1 * x2v * 0.5f * (1.0f + erff(x2v * 0.70710678118654752f));
        G[grow + col] = (_Float16)g;
      }
    }
  }
}

// ---------------- GEMM2 + bias + weight scale + scatter ----------------
__global__ __launch_bounds__(256) void k_gemm2_out(
    const _Float16* __restrict__ G, const _Float16* __restrict__ Vt,
    const float* __restrict__ ob, const int* __restrict__ offs,
    const int* __restrict__ counts, const int* __restrict__ perm,
    const float* __restrict__ wgt, float* __restrict__ out) {
  int e = blockIdx.y >> 6;
  int m0 = (blockIdx.y & 63) * 128;
  int n_e = counts[e];
  if (m0 >= n_e) return;
  int seg = offs[e];
  int n0 = blockIdx.x * 128;

  __shared__ __align__(16) _Float16 As[128][32];
  __shared__ __align__(16) _Float16 Bs[128][32];

  int tid = threadIdx.x, wid = tid >> 6, lane = tid & 63;
  int wm = wid >> 1, wn = wid & 1;
  const _Float16* Ve = Vt + (size_t)e * (1024ull * 2048ull);
  const float* obe = ob + e * 1024;

  int srow = tid >> 2, scol = (tid & 3) * 8;
  int ar0 = min(seg + m0 + srow, T_TOK - 1);
  int ar1 = min(seg + m0 + 64 + srow, T_TOK - 1);
  const _Float16* gA0 = G + (size_t)ar0 * FDIM + scol;
  const _Float16* gA1 = G + (size_t)ar1 * FDIM + scol;
  const _Float16* gB0 = Ve + (size_t)(n0 + srow) * FDIM + scol;
  const _Float16* gB1 = Ve + (size_t)(n0 + 64 + srow) * FDIM + scol;
  _Float16* lA0 = &As[0][0] + tid * 8;
  _Float16* lA1 = &As[0][0] + 2048 + tid * 8;
  _Float16* lB0 = &Bs[0][0] + tid * 8;
  _Float16* lB1 = &Bs[0][0] + 2048 + tid * 8;

  f32x4 acc[4][4];
#pragma unroll
  for (int a = 0; a < 4; ++a)
#pragma unroll
    for (int b = 0; b < 4; ++b) acc[a][b] = (f32x4){0.f, 0.f, 0.f, 0.f};

  int lr = lane & 15;
  int lk = (lane >> 4) * 8;

  for (int k0 = 0; k0 < FDIM; k0 += 32) {
    gl_lds16(gA0 + k0, lA0);
    gl_lds16(gA1 + k0, lA1);
    gl_lds16(gB0 + k0, lB0);
    gl_lds16(gB1 + k0, lB1);
    __syncthreads();
    f16x8 a[4], b[4];
#pragma unroll
    for (int mf = 0; mf < 4; ++mf)
      a[mf] = *(const f16x8*)&As[wm * 64 + mf * 16 + lr][lk];
#pragma unroll
    for (int nf = 0; nf < 4; ++nf)
      b[nf] = *(const f16x8*)&Bs[wn * 64 + nf * 16 + lr][lk];
#pragma unroll
    for (int mf = 0; mf < 4; ++mf)
#pragma unroll
      for (int nf = 0; nf < 4; ++nf)
        acc[mf][nf] = __builtin_amdgcn_mfma_f32_16x16x32_f16(a[mf], b[nf], acc[mf][nf], 0, 0, 0);
    __syncthreads();
  }

  int lk4 = (lane >> 4) * 4;
#pragma unroll
  for (int mf = 0; mf < 4; ++mf) {
#pragma unroll
    for (int i = 0; i < 4; ++i) {
      int pl = m0 + wm * 64 + mf * 16 + lk4 + i;
      if (pl >= n_e) continue;
      int p = seg + pl;
      int t = perm[p];
      float wv = wgt[t];
      float* orow = out + (size_t)t * DDIM;
#pragma unroll
      for (int nf = 0; nf < 4; ++nf) {
        int col = n0 + wn * 64 + nf * 16 + lr;
        orow[col] = (acc[mf][nf][i] + obe[col]) * wv;
      }
    }
  }
}

extern "C" void kernel_launch(void* const* d_in, const int* in_sizes, int n_in,
                              void* d_out, int out_size, void* d_ws, size_t ws_size,
                              hipStream_t stream) {
  const float* x   = (const float*)d_in[0];
  const float* gW  = (const float*)d_in[1];
  const float* gb  = (const float*)d_in[2];
  const float* fcW = (const float*)d_in[3];
  const float* fcb = (const float*)d_in[4];
  const float* oW  = (const float*)d_in[5];
  const float* ob  = (const float*)d_in[6];
  float* out = (float*)d_out;

  char* p = (char*)d_ws;
  _Float16* fcWt  = (_Float16*)p; p += (size_t)NEXP * 4096 * 1024 * 2;   // 67.1 MB
  _Float16* outWt = (_Float16*)p; p += (size_t)NEXP * 1024 * 2048 * 2;   // 33.6 MB
  _Float16* Xg    = (_Float16*)p; p += (size_t)T_TOK * DDIM * 2;         // 16.8 MB
  _Float16* G     = (_Float16*)p; p += (size_t)T_TOK * FDIM * 2;         // 33.6 MB
  int*   idx     = (int*)p;   p += T_TOK * 4;
  float* wgt     = (float*)p; p += T_TOK * 4;
  int*   perm    = (int*)p;   p += T_TOK * 4;
  int*   counts  = (int*)p;   p += 64;
  int*   offs    = (int*)p;   p += 64;

  k_gate<<<T_TOK / 8, 256, 0, stream>>>(x, gW, gb, idx, wgt);
  k_route<<<1, 1024, 0, stream>>>(idx, wgt, perm, counts, offs,
                                  out + (size_t)T_TOK * DDIM);
  // weight conversions (independent of routing)
  k_transpose_cvt<<<dim3(4096 / 32, 1024 / 32, NEXP), 256, 0, stream>>>(fcW, fcWt, 1024, 4096);
  k_transpose_cvt<<<dim3(1024 / 32, 2048 / 32, NEXP), 256, 0, stream>>>(oW, outWt, 2048, 1024);
  k_gather_cvt<<<T_TOK, 256, 0, stream>>>(x, perm, Xg);
  k_gemm1_glu<<<dim3(2048 / 64, NEXP * 64), 256, 0, stream>>>(Xg, fcWt, fcb, offs, counts, G);
  k_gemm2_out<<<dim3(1024 / 128, NEXP * 64), 256, 0, stream>>>(G, outWt, ob, offs, counts, perm, wgt, out);
}